// Round 4
// baseline (394.228 us; speedup 1.0000x reference)
//
#include <hip/hip_runtime.h>
#include <cstddef>

#define T_LEN 1000
#define B_SZ 64
#define C_IN_ 12
#define D_MODEL_ 128
#define D_INNER_ 256
#define D_STATE_ 16
#define DT_RANK_ 8
#define N_CLS 5
#define TC_ 200   // scan time-chunk for Bm staging

__device__ __forceinline__ float sigmoid_f(float x) {
  if (x >= 0.f) return 1.f / (1.f + expf(-x));
  float e = expf(x);
  return e / (1.f + e);
}
__device__ __forceinline__ float softplus_f(float x) {
  return (x > 0.f) ? (x + log1pf(expf(-x))) : log1pf(expf(x));
}

// K1 v2: fused ip-proj -> in-proj(xm half) -> causal conv -> silu -> u.
// Per-thread 11x8 register tile (8 output rows + 3 halo rows recomputed),
// conv entirely in registers; LDS ~70KB -> 2 blocks/CU.
__global__ __launch_bounds__(256, 2) void k1_u(
    const float* __restrict__ x, const float* __restrict__ ip_w,
    const float* __restrict__ ip_b, const float* __restrict__ in_proj_w,
    const float* __restrict__ conv_w, const float* __restrict__ conv_b,
    float* __restrict__ u_out)
{
  __shared__ float h_s[67][132];     // 35.4 KB, b128-aligned rows, broadcast reads
  __shared__ float w_s[256][20];     // 20.5 KB, 16-K chunk + pad 4
  __shared__ float xa[67][C_IN_];
  __shared__ float ipw_s[D_MODEL_][C_IN_];
  __shared__ float cw_s[D_INNER_][4];
  __shared__ float cb_s[D_INNER_];

  const int tile = blockIdx.x;   // 0..15
  const int b    = blockIdx.y;   // 0..63
  const int t0   = tile * 64;
  const int tid  = threadIdx.x;
  const int tr = tid >> 5, tc = tid & 31;

  for (int f = tid; f < 67 * C_IN_; f += 256) {
    int r = f / C_IN_, c = f - r * C_IN_;
    int t = t0 - 3 + r;
    xa[r][c] = (t >= 0 && t < T_LEN) ? x[((size_t)b * T_LEN + t) * C_IN_ + c] : 0.f;
  }
  for (int f = tid; f < D_MODEL_ * C_IN_; f += 256) ipw_s[f / C_IN_][f % C_IN_] = ip_w[f];
  for (int f = tid; f < D_INNER_ * 4; f += 256) cw_s[f >> 2][f & 3] = conv_w[f];
  if (tid < D_INNER_) cb_s[tid] = conv_b[tid];
  __syncthreads();

  // h tile (67 x 128) into LDS
  for (int f = tid; f < 67 * D_MODEL_; f += 256) {
    int r = f >> 7, d = f & 127;
    float acc = ip_b[d];
#pragma unroll
    for (int c = 0; c < C_IN_; ++c) acc += xa[r][c] * ipw_s[d][c];
    h_s[r][d] = acc;
  }

  // xm rows tr*8-3 .. tr*8+7 (h_s rows tr*8 .. tr*8+10), cols tc+32*jj
  float acc[11][8];
#pragma unroll
  for (int m = 0; m < 11; ++m)
#pragma unroll
    for (int j = 0; j < 8; ++j) acc[m][j] = 0.f;

  for (int kc = 0; kc < D_MODEL_; kc += 16) {
    __syncthreads();
    {
      const float4* wp = (const float4*)(in_proj_w + (size_t)tid * D_MODEL_ + kc);
      float4 q0 = wp[0], q1 = wp[1], q2 = wp[2], q3 = wp[3];
      *(float4*)&w_s[tid][0]  = q0;
      *(float4*)&w_s[tid][4]  = q1;
      *(float4*)&w_s[tid][8]  = q2;
      *(float4*)&w_s[tid][12] = q3;
    }
    __syncthreads();
#pragma unroll
    for (int kk4 = 0; kk4 < 4; ++kk4) {
      float4 a4[11], b4[8];
#pragma unroll
      for (int m = 0; m < 11; ++m)
        a4[m] = *(const float4*)&h_s[tr * 8 + m][kc + kk4 * 4];
#pragma unroll
      for (int jj = 0; jj < 8; ++jj)
        b4[jj] = *(const float4*)&w_s[tc + 32 * jj][kk4 * 4];
#pragma unroll
      for (int m = 0; m < 11; ++m)
#pragma unroll
        for (int jj = 0; jj < 8; ++jj) {
          acc[m][jj] += a4[m].x * b4[jj].x;
          acc[m][jj] += a4[m].y * b4[jj].y;
          acc[m][jj] += a4[m].z * b4[jj].z;
          acc[m][jj] += a4[m].w * b4[jj].w;
        }
    }
  }

  // t<0 zero padding of xm (only tile 0's first 3 halo rows)
  if (t0 == 0 && tr == 0) {
#pragma unroll
    for (int m = 0; m < 3; ++m)
#pragma unroll
      for (int jj = 0; jj < 8; ++jj) acc[m][jj] = 0.f;
  }

  // conv + silu + store (registers only; acc[i+k] = xm row t-3+k for out row i)
  float4 cwv[8];
  float cbv[8];
#pragma unroll
  for (int jj = 0; jj < 8; ++jj) {
    cwv[jj] = *(const float4*)&cw_s[tc + 32 * jj][0];
    cbv[jj] = cb_s[tc + 32 * jj];
  }
#pragma unroll
  for (int i = 0; i < 8; ++i) {
    int t = t0 + tr * 8 + i;
    if (t < T_LEN) {
#pragma unroll
      for (int jj = 0; jj < 8; ++jj) {
        float s = cbv[jj]
          + acc[i + 0][jj] * cwv[jj].x
          + acc[i + 1][jj] * cwv[jj].y
          + acc[i + 2][jj] * cwv[jj].z
          + acc[i + 3][jj] * cwv[jj].w;
        u_out[((size_t)b * T_LEN + t) * D_INNER_ + (tc + 32 * jj)] = s * sigmoid_f(s);
      }
    }
  }
}

// K3 v3: phase1 dbc = u @ xp[0:24].T (u rows straight from global); phase2
// thread-per-n: delta = softplus(dt@dtw.T+b), emits TRANSPOSED delta_T and
// du_T (= delta*u) in [b][d][t] layout for k4's b128 reads.
__global__ __launch_bounds__(256) void k3_delta(
    const float* __restrict__ u, const float* __restrict__ x_proj_w,
    const float* __restrict__ dt_proj_w, const float* __restrict__ dt_proj_b,
    float* __restrict__ delta_T, float* __restrict__ du_T,
    float* __restrict__ bm_out)
{
  __shared__ float4 xp4[24][65];
  __shared__ float dt_s[64][9];

  const int row0 = blockIdx.x * 64;   // 1000 blocks
  const int tid = threadIdx.x;

  for (int f = tid; f < 24 * 64; f += 256) {
    int c = f >> 6, k4 = f & 63;
    xp4[c][k4] = *(const float4*)&x_proj_w[(size_t)c * 256 + k4 * 4];
  }
  const float4 w0 = *(const float4*)&dt_proj_w[(size_t)tid * 8];
  const float4 w1 = *(const float4*)&dt_proj_w[(size_t)tid * 8 + 4];
  const float bias = dt_proj_b[tid];
  __syncthreads();

  // phase 1
  {
    const int r2 = tid >> 3, cg = tid & 7;
    const int ra = 2 * r2;
    const float4* ua4 = (const float4*)(u + (size_t)(row0 + ra) * 256);
    const float4* ub4 = (const float4*)(u + (size_t)(row0 + ra + 1) * 256);
    float a0 = 0.f, a1 = 0.f, a2 = 0.f, b0 = 0.f, b1 = 0.f, b2 = 0.f;
    for (int k4 = 0; k4 < 64; ++k4) {
      float4 a = ua4[k4], b = ub4[k4];
      float4 q0 = xp4[cg * 3 + 0][k4];
      float4 q1 = xp4[cg * 3 + 1][k4];
      float4 q2 = xp4[cg * 3 + 2][k4];
      a0 += a.x * q0.x + a.y * q0.y + a.z * q0.z + a.w * q0.w;
      a1 += a.x * q1.x + a.y * q1.y + a.z * q1.z + a.w * q1.w;
      a2 += a.x * q2.x + a.y * q2.y + a.z * q2.z + a.w * q2.w;
      b0 += b.x * q0.x + b.y * q0.y + b.z * q0.z + b.w * q0.w;
      b1 += b.x * q1.x + b.y * q1.y + b.z * q1.z + b.w * q1.w;
      b2 += b.x * q2.x + b.y * q2.y + b.z * q2.z + b.w * q2.w;
    }
    float va[2][3] = {{a0, a1, a2}, {b0, b1, b2}};
#pragma unroll
    for (int rr = 0; rr < 2; ++rr)
#pragma unroll
      for (int c = 0; c < 3; ++c) {
        int col = cg * 3 + c;
        int row = ra + rr;
        if (col < 8) dt_s[row][col] = va[rr][c];
        else bm_out[((size_t)(row0 + row)) * 16 + (col - 8)] = va[rr][c];
      }
  }
  __syncthreads();

  // phase 2: thread = n; 64 rows, float4 transposed stores
  for (int r4 = 0; r4 < 16; ++r4) {
    float dd[4], xx[4];
#pragma unroll
    for (int rr = 0; rr < 4; ++rr) {
      int r = r4 * 4 + rr;
      float pre = bias
        + dt_s[r][0] * w0.x + dt_s[r][1] * w0.y + dt_s[r][2] * w0.z + dt_s[r][3] * w0.w
        + dt_s[r][4] * w1.x + dt_s[r][5] * w1.y + dt_s[r][6] * w1.z + dt_s[r][7] * w1.w;
      float dlt = softplus_f(pre);
      float uv = u[(size_t)(row0 + r) * 256 + tid];
      dd[rr] = dlt;
      xx[rr] = dlt * uv;
    }
    int row = row0 + r4 * 4;
    int bb = row / 1000;
    int t  = row - bb * 1000;
    if (t <= 996) {
      size_t base = ((size_t)bb * 256 + tid) * 1000 + t;
      *(float4*)&delta_T[base] = make_float4(dd[0], dd[1], dd[2], dd[3]);
      *(float4*)&du_T[base]    = make_float4(xx[0], xx[1], xx[2], xx[3]);
    } else {
#pragma unroll
      for (int rr = 0; rr < 4; ++rr) {
        int rowe = row + rr;
        int be = rowe / 1000;
        int te = rowe - be * 1000;
        size_t ad = ((size_t)be * 256 + tid) * 1000 + te;
        delta_T[ad] = dd[rr];
        du_T[ad]    = xx[rr];
      }
    }
  }
}

// K4 v3: thread = (b, d, n); delta/du read straight from global as b128
// (transposed layout), only Bm staged in LDS.
__global__ __launch_bounds__(256) void k4_scan(
    const float* __restrict__ delta_T, const float* __restrict__ du_T,
    const float* __restrict__ bm, const float* __restrict__ A_log,
    float* __restrict__ state_out)
{
  __shared__ float ba[TC_ / 4][16][4];   // [t4][n][t&3], 12.8 KB

  const int d0 = blockIdx.x * 16;
  const int b  = blockIdx.y;
  const int tid = threadIdx.x;
  const int dl = tid >> 4;
  const int n  = tid & 15;

  const float A2 = -expf(A_log[(size_t)(d0 + dl) * 16 + n]) * 1.4426950408889634f;
  float s = 0.f;

  const float* dp = delta_T + ((size_t)b * 256 + d0 + dl) * 1000;
  const float* xp = du_T    + ((size_t)b * 256 + d0 + dl) * 1000;
  const float* bbase = bm + (size_t)b * T_LEN * 16;

  for (int t0c = 0; t0c < T_LEN; t0c += TC_) {
    __syncthreads();
    for (int f = tid; f < TC_ * 4; f += 256) {
      int t = f >> 2, g = f & 3;
      float4 bv = *(const float4*)&bbase[(size_t)(t0c + t) * 16 + g * 4];
      int t4 = t >> 2, t3 = t & 3, n4 = g * 4;
      ba[t4][n4 + 0][t3] = bv.x; ba[t4][n4 + 1][t3] = bv.y;
      ba[t4][n4 + 2][t3] = bv.z; ba[t4][n4 + 3][t3] = bv.w;
    }
    __syncthreads();
#pragma unroll 2
    for (int t4 = 0; t4 < TC_ / 4; ++t4) {
      float4 dv = *(const float4*)&dp[t0c + t4 * 4];
      float4 xv = *(const float4*)&xp[t0c + t4 * 4];
      float4 bv = *(const float4*)&ba[t4][n][0];
      s = exp2f(dv.x * A2) * s + xv.x * bv.x;
      s = exp2f(dv.y * A2) * s + xv.y * bv.y;
      s = exp2f(dv.z * A2) * s + xv.z * bv.z;
      s = exp2f(dv.w * A2) * s + xv.w * bv.w;
    }
  }
  state_out[((size_t)b * 256 + d0 + dl) * 16 + n] = s;
}

// K5: per-batch head.
__global__ __launch_bounds__(256) void k5_head(
    const float* __restrict__ x, const float* __restrict__ ip_w,
    const float* __restrict__ ip_b, const float* __restrict__ in_proj_w,
    const float* __restrict__ x_proj_w, const float* __restrict__ u,
    const float* __restrict__ state, const float* __restrict__ D_skip,
    const float* __restrict__ out_proj_w, const float* __restrict__ fc1_w,
    const float* __restrict__ fc1_b, const float* __restrict__ fc2_w,
    const float* __restrict__ fc2_b, float* __restrict__ out)
{
  const int b = blockIdx.x, tid = threadIdx.x;
  __shared__ float hl[128], ul[256], zs[256], cm[16], yv[256], ov[128], hid[64];
  if (tid < 128) {
    float acc = ip_b[tid];
    const float* xr = x + ((size_t)b * T_LEN + (T_LEN - 1)) * C_IN_;
#pragma unroll
    for (int c = 0; c < C_IN_; ++c) acc += xr[c] * ip_w[tid * C_IN_ + c];
    hl[tid] = acc;
  }
  ul[tid] = u[((size_t)b * T_LEN + (T_LEN - 1)) * 256 + tid];
  __syncthreads();
  {
    float acc = 0.f;
    const float* w = in_proj_w + (size_t)(256 + tid) * 128;
    for (int k = 0; k < 128; ++k) acc += hl[k] * w[k];
    zs[tid] = acc * sigmoid_f(acc);
  }
  if (tid < 16) {
    float acc = 0.f;
    const float* w = x_proj_w + (size_t)(24 + tid) * 256;
    for (int k = 0; k < 256; ++k) acc += ul[k] * w[k];
    cm[tid] = acc;
  }
  __syncthreads();
  {
    const float* st = state + ((size_t)b * 256 + tid) * 16;
    float acc = 0.f;
#pragma unroll
    for (int n = 0; n < 16; ++n) acc += st[n] * cm[n];
    yv[tid] = (acc + ul[tid] * D_skip[tid]) * zs[tid];
  }
  __syncthreads();
  if (tid < 128) {
    float acc = 0.f;
    const float* w = out_proj_w + (size_t)tid * 256;
    for (int k = 0; k < 256; ++k) acc += yv[k] * w[k];
    ov[tid] = acc;
  }
  __syncthreads();
  if (tid < 64) {
    float acc = fc1_b[tid];
    const float* w = fc1_w + (size_t)tid * 128;
    for (int k = 0; k < 128; ++k) acc += ov[k] * w[k];
    hid[tid] = fmaxf(acc, 0.f);
  }
  __syncthreads();
  if (tid < N_CLS) {
    float acc = fc2_b[tid];
    const float* w = fc2_w + (size_t)tid * 64;
    for (int k = 0; k < 64; ++k) acc += hid[k] * w[k];
    out[b * N_CLS + tid] = acc;
  }
}

extern "C" void kernel_launch(void* const* d_in, const int* in_sizes, int n_in,
                              void* d_out, int out_size, void* d_ws, size_t ws_size,
                              hipStream_t stream) {
  (void)in_sizes; (void)n_in; (void)out_size; (void)ws_size;
  const float* x         = (const float*)d_in[0];
  const float* ip_w      = (const float*)d_in[1];
  const float* ip_b      = (const float*)d_in[2];
  const float* in_proj_w = (const float*)d_in[3];
  const float* conv_w    = (const float*)d_in[4];
  const float* conv_b    = (const float*)d_in[5];
  const float* x_proj_w  = (const float*)d_in[6];
  const float* dt_proj_w = (const float*)d_in[7];
  const float* dt_proj_b = (const float*)d_in[8];
  const float* A_log     = (const float*)d_in[9];
  const float* D_skip    = (const float*)d_in[10];
  const float* out_proj_w= (const float*)d_in[11];
  const float* fc1_w     = (const float*)d_in[12];
  const float* fc1_b     = (const float*)d_in[13];
  const float* fc2_w     = (const float*)d_in[14];
  const float* fc2_b     = (const float*)d_in[15];
  float* out = (float*)d_out;

  float* u       = (float*)d_ws;                         // 16,384,000 f32
  float* delta_T = u + (size_t)64000 * 256;              // 16,384,000 f32 [b][d][t]
  float* du_T    = delta_T + (size_t)64000 * 256;        // 16,384,000 f32 [b][d][t]
  float* bm      = du_T + (size_t)64000 * 256;           // 1,024,000 f32 [b][t][n]
  float* state   = bm + (size_t)64000 * 16;              // 262,144 f32

  k1_u<<<dim3(16, 64), 256, 0, stream>>>(x, ip_w, ip_b, in_proj_w, conv_w, conv_b, u);
  k3_delta<<<1000, 256, 0, stream>>>(u, x_proj_w, dt_proj_w, dt_proj_b,
                                     delta_T, du_T, bm);
  k4_scan<<<dim3(16, 64), 256, 0, stream>>>(delta_T, du_T, bm, A_log, state);
  k5_head<<<64, 256, 0, stream>>>(x, ip_w, ip_b, in_proj_w, x_proj_w, u, state,
                                  D_skip, out_proj_w, fc1_w, fc1_b, fc2_w, fc2_b, out);
}

// Round 5
// 382.641 us; speedup vs baseline: 1.0303x; 1.0303x over previous
//
#include <hip/hip_runtime.h>
#include <cstddef>

#define T_LEN 1000
#define B_SZ 64
#define C_IN_ 12
#define D_MODEL_ 128
#define D_INNER_ 256
#define D_STATE_ 16
#define DT_RANK_ 8
#define N_CLS 5
#define TC_ 200   // scan time-chunk staged in LDS

__device__ __forceinline__ float sigmoid_f(float x) {
  if (x >= 0.f) return 1.f / (1.f + expf(-x));
  float e = expf(x);
  return e / (1.f + e);
}
__device__ __forceinline__ float softplus_f(float x) {
  return (x > 0.f) ? (x + log1pf(expf(-x))) : log1pf(expf(x));
}

// K1 v3: fused ip-proj -> in-proj(xm half) -> causal conv -> silu -> u.
// acc[8][8] per thread (no spill), 3 halo rows via hacc (+4.7% MACs),
// conv cross-thread rows exchanged through LDS halo buffer that REUSES the
// dead h_s/w_s storage (union) -> LDS ~70KB -> 2 blocks/CU.
__global__ __launch_bounds__(256) void k1_u(
    const float* __restrict__ x, const float* __restrict__ ip_w,
    const float* __restrict__ ip_b, const float* __restrict__ in_proj_w,
    const float* __restrict__ conv_w, const float* __restrict__ conv_b,
    float* __restrict__ u_out)
{
  __shared__ union {
    struct {
      float h[67][132];   // h tile, b128-aligned rows, broadcast reads
      float w[256][20];   // W1 16-K chunk + pad 4
    } g;
    float halo[8][3][256]; // xm rows tr*8-3..tr*8-1 for each group (after GEMM)
  } sm;
  __shared__ float xa[67][C_IN_];
  __shared__ float ipw_s[D_MODEL_][C_IN_];
  __shared__ float cw_s[D_INNER_][4];
  __shared__ float cb_s[D_INNER_];

  const int tile = blockIdx.x;   // 0..15
  const int b    = blockIdx.y;   // 0..63
  const int t0   = tile * 64;
  const int tid  = threadIdx.x;
  const int tr = tid >> 5, tc = tid & 31;

  for (int f = tid; f < 67 * C_IN_; f += 256) {
    int r = f / C_IN_, c = f - r * C_IN_;
    int t = t0 - 3 + r;
    xa[r][c] = (t >= 0 && t < T_LEN) ? x[((size_t)b * T_LEN + t) * C_IN_ + c] : 0.f;
  }
  for (int f = tid; f < D_MODEL_ * C_IN_; f += 256) ipw_s[f / C_IN_][f % C_IN_] = ip_w[f];
  for (int f = tid; f < D_INNER_ * 4; f += 256) cw_s[f >> 2][f & 3] = conv_w[f];
  if (tid < D_INNER_) cb_s[tid] = conv_b[tid];
  __syncthreads();

  // h tile (67 x 128) into LDS
  for (int f = tid; f < 67 * D_MODEL_; f += 256) {
    int r = f >> 7, d = f & 127;
    float acc = ip_b[d];
#pragma unroll
    for (int c = 0; c < C_IN_; ++c) acc += xa[r][c] * ipw_s[d][c];
    sm.g.h[r][d] = acc;
  }

  // xm rows t0+tr*8 .. +7 (cols tc+32jj) + 3 block-halo rows (col tid)
  float acc[8][8];
#pragma unroll
  for (int m = 0; m < 8; ++m)
#pragma unroll
    for (int j = 0; j < 8; ++j) acc[m][j] = 0.f;
  float hacc[3] = {0.f, 0.f, 0.f};

  for (int kc = 0; kc < D_MODEL_; kc += 16) {
    __syncthreads();
    {
      const float4* wp = (const float4*)(in_proj_w + (size_t)tid * D_MODEL_ + kc);
      float4 q0 = wp[0], q1 = wp[1], q2 = wp[2], q3 = wp[3];
      *(float4*)&sm.g.w[tid][0]  = q0;
      *(float4*)&sm.g.w[tid][4]  = q1;
      *(float4*)&sm.g.w[tid][8]  = q2;
      *(float4*)&sm.g.w[tid][12] = q3;
    }
    __syncthreads();
#pragma unroll
    for (int kk4 = 0; kk4 < 4; ++kk4) {
      float4 a4[8], b4[8];
#pragma unroll
      for (int m = 0; m < 8; ++m)
        a4[m] = *(const float4*)&sm.g.h[3 + tr * 8 + m][kc + kk4 * 4];
#pragma unroll
      for (int jj = 0; jj < 8; ++jj)
        b4[jj] = *(const float4*)&sm.g.w[tc + 32 * jj][kk4 * 4];
#pragma unroll
      for (int m = 0; m < 8; ++m)
#pragma unroll
        for (int jj = 0; jj < 8; ++jj) {
          acc[m][jj] += a4[m].x * b4[jj].x;
          acc[m][jj] += a4[m].y * b4[jj].y;
          acc[m][jj] += a4[m].z * b4[jj].z;
          acc[m][jj] += a4[m].w * b4[jj].w;
        }
      // block-halo rows t0-3..t0-1, one column (tid) per thread
      float4 bw = *(const float4*)&sm.g.w[tid][kk4 * 4];
      float4 h0 = *(const float4*)&sm.g.h[0][kc + kk4 * 4];
      float4 h1 = *(const float4*)&sm.g.h[1][kc + kk4 * 4];
      float4 h2 = *(const float4*)&sm.g.h[2][kc + kk4 * 4];
      hacc[0] += h0.x * bw.x + h0.y * bw.y + h0.z * bw.z + h0.w * bw.w;
      hacc[1] += h1.x * bw.x + h1.y * bw.y + h1.z * bw.z + h1.w * bw.w;
      hacc[2] += h2.x * bw.x + h2.y * bw.y + h2.z * bw.z + h2.w * bw.w;
    }
  }
  __syncthreads();   // all reads of sm.g done; safe to overwrite as halo

  // publish halo rows: group tr+1 needs my rows 5..7; group 0 needs hacc
#pragma unroll
  for (int k = 0; k < 3; ++k) {
    if (tr < 7) {
#pragma unroll
      for (int jj = 0; jj < 8; ++jj)
        sm.halo[tr + 1][k][tc + 32 * jj] = acc[5 + k][jj];
    }
    sm.halo[0][k][tid] = (t0 == 0) ? 0.f : hacc[k];
  }
  __syncthreads();

  // conv + silu + store
  float4 cwv[8];
  float cbv[8];
#pragma unroll
  for (int jj = 0; jj < 8; ++jj) {
    cwv[jj] = *(const float4*)&cw_s[tc + 32 * jj][0];
    cbv[jj] = cb_s[tc + 32 * jj];
  }
#pragma unroll
  for (int i = 0; i < 8; ++i) {
    int t = t0 + tr * 8 + i;
    if (t < T_LEN) {
#pragma unroll
      for (int jj = 0; jj < 8; ++jj) {
        int col = tc + 32 * jj;
        float x0 = (i >= 3) ? acc[i - 3][jj] : sm.halo[tr][i][col];
        float x1 = (i >= 2) ? acc[i - 2][jj] : sm.halo[tr][i + 1][col];
        float x2 = (i >= 1) ? acc[i - 1][jj] : sm.halo[tr][i + 2][col];
        float x3 = acc[i][jj];
        float s = cbv[jj] + x0 * cwv[jj].x + x1 * cwv[jj].y
                          + x2 * cwv[jj].z + x3 * cwv[jj].w;
        u_out[((size_t)b * T_LEN + t) * D_INNER_ + col] = s * sigmoid_f(s);
      }
    }
  }
}

// K3 (R3-proven): lean LDS. Phase 1: dbc = u @ xp[0:24].T with u read straight
// from global (float4 broadcast). Phase 2: delta = softplus(dt @ dtw.T + b).
__global__ __launch_bounds__(256) void k3_delta(
    const float* __restrict__ u, const float* __restrict__ x_proj_w,
    const float* __restrict__ dt_proj_w, const float* __restrict__ dt_proj_b,
    float* __restrict__ delta_out, float* __restrict__ bm_out)
{
  __shared__ float4 xp4[24][65];
  __shared__ float4 dtw4[256][2];
  __shared__ float dt_s[64][9];
  __shared__ float dtb_s[256];

  const int row0 = blockIdx.x * 64;   // 1000 blocks
  const int tid = threadIdx.x;

  for (int f = tid; f < 24 * 64; f += 256) {
    int c = f >> 6, k4 = f & 63;
    xp4[c][k4] = *(const float4*)&x_proj_w[(size_t)c * 256 + k4 * 4];
  }
  for (int f = tid; f < 512; f += 256) {
    int n = f >> 1, hh = f & 1;
    dtw4[n][hh] = *(const float4*)&dt_proj_w[(size_t)n * 8 + hh * 4];
  }
  dtb_s[tid] = dt_proj_b[tid];
  __syncthreads();

  // phase 1
  {
    const int r2 = tid >> 3, cg = tid & 7;
    const int ra = 2 * r2;
    const float4* ua4 = (const float4*)(u + (size_t)(row0 + ra) * 256);
    const float4* ub4 = (const float4*)(u + (size_t)(row0 + ra + 1) * 256);
    float a0 = 0.f, a1 = 0.f, a2 = 0.f, b0 = 0.f, b1 = 0.f, b2 = 0.f;
    for (int k4 = 0; k4 < 64; ++k4) {
      float4 a = ua4[k4], b = ub4[k4];
      float4 w0 = xp4[cg * 3 + 0][k4];
      float4 w1 = xp4[cg * 3 + 1][k4];
      float4 w2 = xp4[cg * 3 + 2][k4];
      a0 += a.x * w0.x + a.y * w0.y + a.z * w0.z + a.w * w0.w;
      a1 += a.x * w1.x + a.y * w1.y + a.z * w1.z + a.w * w1.w;
      a2 += a.x * w2.x + a.y * w2.y + a.z * w2.z + a.w * w2.w;
      b0 += b.x * w0.x + b.y * w0.y + b.z * w0.z + b.w * w0.w;
      b1 += b.x * w1.x + b.y * w1.y + b.z * w1.z + b.w * w1.w;
      b2 += b.x * w2.x + b.y * w2.y + b.z * w2.z + b.w * w2.w;
    }
    float va[2][3] = {{a0, a1, a2}, {b0, b1, b2}};
#pragma unroll
    for (int rr = 0; rr < 2; ++rr)
#pragma unroll
      for (int c = 0; c < 3; ++c) {
        int col = cg * 3 + c;
        int row = ra + rr;
        if (col < 8) dt_s[row][col] = va[rr][c];
        else bm_out[((size_t)(row0 + row)) * 16 + (col - 8)] = va[rr][c];
      }
  }
  __syncthreads();

  // phase 2
  {
    const int r = tid >> 2, q = tid & 3;
    float dtv[8];
#pragma unroll
    for (int j = 0; j < 8; ++j) dtv[j] = dt_s[r][j];
    float* drow = delta_out + (size_t)(row0 + r) * 256;
    for (int cc = 0; cc < 64; ++cc) {
      int n = 4 * cc + q;
      float4 w0 = dtw4[n][0], w1 = dtw4[n][1];
      float pre = dtb_s[n]
        + dtv[0] * w0.x + dtv[1] * w0.y + dtv[2] * w0.z + dtv[3] * w0.w
        + dtv[4] * w1.x + dtv[5] * w1.y + dtv[6] * w1.z + dtv[7] * w1.w;
      drow[n] = softplus_f(pre);
    }
  }
}

// K4 (R3-proven): thread = (b, d, n); float4 global staging into LDS.
__global__ __launch_bounds__(256) void k4_scan(
    const float* __restrict__ delta, const float* __restrict__ u,
    const float* __restrict__ bm, const float* __restrict__ A_log,
    float* __restrict__ state_out)
{
  __shared__ float da[TC_ / 4][16][4];
  __shared__ float ua[TC_ / 4][16][4];
  __shared__ float ba[TC_ / 4][16][4];

  const int d0 = blockIdx.x * 16;
  const int b  = blockIdx.y;
  const int tid = threadIdx.x;
  const int dl = tid >> 4;
  const int n  = tid & 15;

  const float A2 = -expf(A_log[(size_t)(d0 + dl) * 16 + n]) * 1.4426950408889634f;
  float s = 0.f;

  const float* dbase = delta + (size_t)b * T_LEN * 256 + d0;
  const float* ubase = u     + (size_t)b * T_LEN * 256 + d0;
  const float* bbase = bm    + (size_t)b * T_LEN * 16;

  for (int t0 = 0; t0 < T_LEN; t0 += TC_) {
    __syncthreads();
    for (int f = tid; f < TC_ * 4; f += 256) {
      int t = f >> 2, g = f & 3;
      float4 dv = *(const float4*)&dbase[(size_t)(t0 + t) * 256 + g * 4];
      float4 uv = *(const float4*)&ubase[(size_t)(t0 + t) * 256 + g * 4];
      float4 bv = *(const float4*)&bbase[(size_t)(t0 + t) * 16 + g * 4];
      int t4 = t >> 2, t3 = t & 3, d4 = g * 4;
      da[t4][d4 + 0][t3] = dv.x; da[t4][d4 + 1][t3] = dv.y;
      da[t4][d4 + 2][t3] = dv.z; da[t4][d4 + 3][t3] = dv.w;
      ua[t4][d4 + 0][t3] = dv.x * uv.x; ua[t4][d4 + 1][t3] = dv.y * uv.y;
      ua[t4][d4 + 2][t3] = dv.z * uv.z; ua[t4][d4 + 3][t3] = dv.w * uv.w;
      ba[t4][d4 + 0][t3] = bv.x; ba[t4][d4 + 1][t3] = bv.y;
      ba[t4][d4 + 2][t3] = bv.z; ba[t4][d4 + 3][t3] = bv.w;
    }
    __syncthreads();
#pragma unroll 2
    for (int t4 = 0; t4 < TC_ / 4; ++t4) {
      float4 dv = *(const float4*)&da[t4][dl][0];
      float4 uv = *(const float4*)&ua[t4][dl][0];
      float4 bv = *(const float4*)&ba[t4][n][0];
      s = exp2f(dv.x * A2) * s + uv.x * bv.x;
      s = exp2f(dv.y * A2) * s + uv.y * bv.y;
      s = exp2f(dv.z * A2) * s + uv.z * bv.z;
      s = exp2f(dv.w * A2) * s + uv.w * bv.w;
    }
  }
  state_out[((size_t)b * 256 + d0 + dl) * 16 + n] = s;
}

// K5: per-batch head.
__global__ __launch_bounds__(256) void k5_head(
    const float* __restrict__ x, const float* __restrict__ ip_w,
    const float* __restrict__ ip_b, const float* __restrict__ in_proj_w,
    const float* __restrict__ x_proj_w, const float* __restrict__ u,
    const float* __restrict__ state, const float* __restrict__ D_skip,
    const float* __restrict__ out_proj_w, const float* __restrict__ fc1_w,
    const float* __restrict__ fc1_b, const float* __restrict__ fc2_w,
    const float* __restrict__ fc2_b, float* __restrict__ out)
{
  const int b = blockIdx.x, tid = threadIdx.x;
  __shared__ float hl[128], ul[256], zs[256], cm[16], yv[256], ov[128], hid[64];
  if (tid < 128) {
    float acc = ip_b[tid];
    const float* xr = x + ((size_t)b * T_LEN + (T_LEN - 1)) * C_IN_;
#pragma unroll
    for (int c = 0; c < C_IN_; ++c) acc += xr[c] * ip_w[tid * C_IN_ + c];
    hl[tid] = acc;
  }
  ul[tid] = u[((size_t)b * T_LEN + (T_LEN - 1)) * 256 + tid];
  __syncthreads();
  {
    float acc = 0.f;
    const float* w = in_proj_w + (size_t)(256 + tid) * 128;
    for (int k = 0; k < 128; ++k) acc += hl[k] * w[k];
    zs[tid] = acc * sigmoid_f(acc);
  }
  if (tid < 16) {
    float acc = 0.f;
    const float* w = x_proj_w + (size_t)(24 + tid) * 256;
    for (int k = 0; k < 256; ++k) acc += ul[k] * w[k];
    cm[tid] = acc;
  }
  __syncthreads();
  {
    const float* st = state + ((size_t)b * 256 + tid) * 16;
    float acc = 0.f;
#pragma unroll
    for (int n = 0; n < 16; ++n) acc += st[n] * cm[n];
    yv[tid] = (acc + ul[tid] * D_skip[tid]) * zs[tid];
  }
  __syncthreads();
  if (tid < 128) {
    float acc = 0.f;
    const float* w = out_proj_w + (size_t)tid * 256;
    for (int k = 0; k < 256; ++k) acc += yv[k] * w[k];
    ov[tid] = acc;
  }
  __syncthreads();
  if (tid < 64) {
    float acc = fc1_b[tid];
    const float* w = fc1_w + (size_t)tid * 128;
    for (int k = 0; k < 128; ++k) acc += ov[k] * w[k];
    hid[tid] = fmaxf(acc, 0.f);
  }
  __syncthreads();
  if (tid < N_CLS) {
    float acc = fc2_b[tid];
    const float* w = fc2_w + (size_t)tid * 64;
    for (int k = 0; k < 64; ++k) acc += hid[k] * w[k];
    out[b * N_CLS + tid] = acc;
  }
}

extern "C" void kernel_launch(void* const* d_in, const int* in_sizes, int n_in,
                              void* d_out, int out_size, void* d_ws, size_t ws_size,
                              hipStream_t stream) {
  (void)in_sizes; (void)n_in; (void)out_size; (void)ws_size;
  const float* x         = (const float*)d_in[0];
  const float* ip_w      = (const float*)d_in[1];
  const float* ip_b      = (const float*)d_in[2];
  const float* in_proj_w = (const float*)d_in[3];
  const float* conv_w    = (const float*)d_in[4];
  const float* conv_b    = (const float*)d_in[5];
  const float* x_proj_w  = (const float*)d_in[6];
  const float* dt_proj_w = (const float*)d_in[7];
  const float* dt_proj_b = (const float*)d_in[8];
  const float* A_log     = (const float*)d_in[9];
  const float* D_skip    = (const float*)d_in[10];
  const float* out_proj_w= (const float*)d_in[11];
  const float* fc1_w     = (const float*)d_in[12];
  const float* fc1_b     = (const float*)d_in[13];
  const float* fc2_w     = (const float*)d_in[14];
  const float* fc2_b     = (const float*)d_in[15];
  float* out = (float*)d_out;

  float* u     = (float*)d_ws;                       // 64000*256 f32
  float* delta = u + (size_t)64000 * 256;            // 64000*256 f32
  float* bm    = delta + (size_t)64000 * 256;        // 64000*16 f32
  float* state = bm + (size_t)64000 * 16;            // 64*256*16 f32

  k1_u<<<dim3(16, 64), 256, 0, stream>>>(x, ip_w, ip_b, in_proj_w, conv_w, conv_b, u);
  k3_delta<<<1000, 256, 0, stream>>>(u, x_proj_w, dt_proj_w, dt_proj_b, delta, bm);
  k4_scan<<<dim3(16, 64), 256, 0, stream>>>(delta, u, bm, A_log, state);
  k5_head<<<64, 256, 0, stream>>>(x, ip_w, ip_b, in_proj_w, x_proj_w, u, state,
                                  D_skip, out_proj_w, fc1_w, fc1_b, fc2_w, fc2_b, out);
}

// Round 6
// 336.596 us; speedup vs baseline: 1.1712x; 1.1368x over previous
//
#include <hip/hip_runtime.h>
#include <cstddef>

#define T_LEN 1000
#define B_SZ 64
#define C_IN_ 12
#define D_MODEL_ 128
#define D_INNER_ 256
#define D_STATE_ 16
#define DT_RANK_ 8
#define N_CLS 5

__device__ __forceinline__ float sigmoid_f(float x) {
  if (x >= 0.f) return 1.f / (1.f + expf(-x));
  float e = expf(x);
  return e / (1.f + e);
}
__device__ __forceinline__ float softplus_f(float x) {
  return (x > 0.f) ? (x + log1pf(expf(-x))) : log1pf(expf(x));
}

// K1 v5: fused ip-proj -> in-proj(xm half) -> causal conv -> silu -> u.
// acc[8][8]/thread, k-major W tile in LDS (scalar b32 fragment reads, lanes on
// consecutive n -> conflict-free by construction). LDS = 50 KB exactly
// (h 34304 + w 16896, halo unioned) -> 3 blocks/CU. Conv params from global.
__global__ __launch_bounds__(256) void k1_u(
    const float* __restrict__ x, const float* __restrict__ ip_w,
    const float* __restrict__ ip_b, const float* __restrict__ in_proj_w,
    const float* __restrict__ conv_w, const float* __restrict__ conv_b,
    float* __restrict__ u_out)
{
  __shared__ union {
    struct {
      float h[67][128];     // 34304 B : h rows t0-3 .. t0+63
      float w[16][264];     // 16896 B : k-major W chunk (16 k x 256 n + pad 8)
    } g;
    float halo[8][3][256];  // 24576 B : reused after GEMM for conv halo
  } sm;

  const int tile = blockIdx.x;   // 0..15
  const int b    = blockIdx.y;   // 0..63
  const int t0   = tile * 64;
  const int tid  = threadIdx.x;
  const int tr = tid >> 5, tc = tid & 31;

  // h tile (67 x 128) straight into LDS; x and ip_w read from global (L2/L3).
  for (int f = tid; f < 67 * D_MODEL_; f += 256) {
    int r = f >> 7, d = f & 127;
    int t = t0 - 3 + r;
    float acc = ip_b[d];
    if (t >= 0) {   // t < 0 rows: value irrelevant (xm forced 0 below)
      const float* xr = x + ((size_t)b * T_LEN + t) * C_IN_;
      const float* wr = ip_w + d * C_IN_;
#pragma unroll
      for (int c = 0; c < C_IN_; ++c) acc += xr[c] * wr[c];
    }
    sm.g.h[r][d] = acc;
  }

  float acc[8][8];
#pragma unroll
  for (int m = 0; m < 8; ++m)
#pragma unroll
    for (int j = 0; j < 8; ++j) acc[m][j] = 0.f;
  float hacc[3] = {0.f, 0.f, 0.f};

  for (int kc = 0; kc < D_MODEL_; kc += 16) {
    __syncthreads();
    {   // stage W chunk k-major: thread = n, scatter 16 b32 (lanes consec n)
      const float* wp = in_proj_w + (size_t)tid * D_MODEL_ + kc;
#pragma unroll
      for (int q = 0; q < 4; ++q) {
        float4 v = *(const float4*)&wp[q * 4];
        sm.g.w[q * 4 + 0][tid] = v.x;
        sm.g.w[q * 4 + 1][tid] = v.y;
        sm.g.w[q * 4 + 2][tid] = v.z;
        sm.g.w[q * 4 + 3][tid] = v.w;
      }
    }
    __syncthreads();
#pragma unroll
    for (int kk4 = 0; kk4 < 4; ++kk4) {
      float4 a4[8];
#pragma unroll
      for (int m = 0; m < 8; ++m)
        a4[m] = *(const float4*)&sm.g.h[3 + tr * 8 + m][kc + kk4 * 4];
      float4 h0 = *(const float4*)&sm.g.h[0][kc + kk4 * 4];
      float4 h1 = *(const float4*)&sm.g.h[1][kc + kk4 * 4];
      float4 h2 = *(const float4*)&sm.g.h[2][kc + kk4 * 4];
#pragma unroll
      for (int c = 0; c < 4; ++c) {
        const int kk = kk4 * 4 + c;
        float bb[8];
#pragma unroll
        for (int jj = 0; jj < 8; ++jj) bb[jj] = sm.g.w[kk][tc + 32 * jj];
        const float aw = sm.g.w[kk][tid];
#pragma unroll
        for (int m = 0; m < 8; ++m) {
          const float av = ((const float*)&a4[m])[c];
#pragma unroll
          for (int jj = 0; jj < 8; ++jj) acc[m][jj] += av * bb[jj];
        }
        hacc[0] += ((const float*)&h0)[c] * aw;
        hacc[1] += ((const float*)&h1)[c] * aw;
        hacc[2] += ((const float*)&h2)[c] * aw;
      }
    }
  }
  __syncthreads();   // all reads of sm.g done; safe to overwrite as halo

  // publish halo rows: group tr+1 needs my rows 5..7; group 0 needs hacc
#pragma unroll
  for (int k = 0; k < 3; ++k) {
    if (tr < 7) {
#pragma unroll
      for (int jj = 0; jj < 8; ++jj)
        sm.halo[tr + 1][k][tc + 32 * jj] = acc[5 + k][jj];
    }
    sm.halo[0][k][tid] = (t0 == 0) ? 0.f : hacc[k];
  }
  __syncthreads();

  // conv + silu + store; conv params straight from global (L2-hot)
  float4 cwv[8];
  float cbv[8];
#pragma unroll
  for (int jj = 0; jj < 8; ++jj) {
    cwv[jj] = *(const float4*)&conv_w[(tc + 32 * jj) * 4];
    cbv[jj] = conv_b[tc + 32 * jj];
  }
#pragma unroll
  for (int i = 0; i < 8; ++i) {
    int t = t0 + tr * 8 + i;
#pragma unroll
    for (int jj = 0; jj < 8; ++jj) {
      int col = tc + 32 * jj;
      float x0 = (i >= 3) ? acc[i - 3][jj] : sm.halo[tr][i][col];
      float x1 = (i >= 2) ? acc[i - 2][jj] : sm.halo[tr][i + 1][col];
      float x2 = (i >= 1) ? acc[i - 1][jj] : sm.halo[tr][i + 2][col];
      float x3 = acc[i][jj];
      float s = cbv[jj] + x0 * cwv[jj].x + x1 * cwv[jj].y
                        + x2 * cwv[jj].z + x3 * cwv[jj].w;
      u_out[((size_t)b * T_LEN + t) * D_INNER_ + col] = s * sigmoid_f(s);
    }
  }
}

// K3 v5: phase1 dbc = u @ xp[0:24].T (u from global, float4 broadcast);
// phase2 thread-per-n: delta = softplus(dt@dtw.T+b), emits delta AND du=delta*u
// both in coalesced [t][d] layout.
__global__ __launch_bounds__(256) void k3_delta(
    const float* __restrict__ u, const float* __restrict__ x_proj_w,
    const float* __restrict__ dt_proj_w, const float* __restrict__ dt_proj_b,
    float* __restrict__ delta_out, float* __restrict__ du_out,
    float* __restrict__ bm_out)
{
  __shared__ float4 xp4[24][65];
  __shared__ float dt_s[64][9];

  const int row0 = blockIdx.x * 64;   // 1000 blocks
  const int tid = threadIdx.x;

  for (int f = tid; f < 24 * 64; f += 256) {
    int c = f >> 6, k4 = f & 63;
    xp4[c][k4] = *(const float4*)&x_proj_w[(size_t)c * 256 + k4 * 4];
  }
  const float4 w0 = *(const float4*)&dt_proj_w[(size_t)tid * 8];
  const float4 w1 = *(const float4*)&dt_proj_w[(size_t)tid * 8 + 4];
  const float bias = dt_proj_b[tid];
  __syncthreads();

  // phase 1
  {
    const int r2 = tid >> 3, cg = tid & 7;
    const int ra = 2 * r2;
    const float4* ua4 = (const float4*)(u + (size_t)(row0 + ra) * 256);
    const float4* ub4 = (const float4*)(u + (size_t)(row0 + ra + 1) * 256);
    float a0 = 0.f, a1 = 0.f, a2 = 0.f, b0 = 0.f, b1 = 0.f, b2 = 0.f;
    for (int k4 = 0; k4 < 64; ++k4) {
      float4 a = ua4[k4], b = ub4[k4];
      float4 q0 = xp4[cg * 3 + 0][k4];
      float4 q1 = xp4[cg * 3 + 1][k4];
      float4 q2 = xp4[cg * 3 + 2][k4];
      a0 += a.x * q0.x + a.y * q0.y + a.z * q0.z + a.w * q0.w;
      a1 += a.x * q1.x + a.y * q1.y + a.z * q1.z + a.w * q1.w;
      a2 += a.x * q2.x + a.y * q2.y + a.z * q2.z + a.w * q2.w;
      b0 += b.x * q0.x + b.y * q0.y + b.z * q0.z + b.w * q0.w;
      b1 += b.x * q1.x + b.y * q1.y + b.z * q1.z + b.w * q1.w;
      b2 += b.x * q2.x + b.y * q2.y + b.z * q2.z + b.w * q2.w;
    }
    float va[2][3] = {{a0, a1, a2}, {b0, b1, b2}};
#pragma unroll
    for (int rr = 0; rr < 2; ++rr)
#pragma unroll
      for (int c = 0; c < 3; ++c) {
        int col = cg * 3 + c;
        int row = ra + rr;
        if (col < 8) dt_s[row][col] = va[rr][c];
        else bm_out[((size_t)(row0 + row)) * 16 + (col - 8)] = va[rr][c];
      }
  }
  __syncthreads();

  // phase 2: thread = n; coalesced b32 stores of delta and du
  for (int r = 0; r < 64; ++r) {
    float pre = bias
      + dt_s[r][0] * w0.x + dt_s[r][1] * w0.y + dt_s[r][2] * w0.z + dt_s[r][3] * w0.w
      + dt_s[r][4] * w1.x + dt_s[r][5] * w1.y + dt_s[r][6] * w1.z + dt_s[r][7] * w1.w;
    float dlt = softplus_f(pre);
    size_t o = (size_t)(row0 + r) * 256 + tid;
    float uv = u[o];
    delta_out[o] = dlt;
    du_out[o] = dlt * uv;
  }
}

// K4 v6: NO LDS. thread = (b, d, n). delta/du read as 16-lane-broadcast b32
// from global (wave = 4 distinct addrs = 1 txn); Bm as coalesced 64B broadcast
// (16x reuse L2-resident). HBM-bound ~132 MB.
__global__ __launch_bounds__(256) void k4_scan(
    const float* __restrict__ delta, const float* __restrict__ du,
    const float* __restrict__ bm, const float* __restrict__ A_log,
    float* __restrict__ state_out)
{
  const int d0 = blockIdx.x * 16;
  const int b  = blockIdx.y;
  const int tid = threadIdx.x;
  const int dl = tid >> 4;
  const int n  = tid & 15;
  const int d  = d0 + dl;

  const float A2 = -expf(A_log[(size_t)d * 16 + n]) * 1.4426950408889634f;
  float s = 0.f;

  const float* dp = delta + (size_t)b * T_LEN * 256 + d;
  const float* xp = du    + (size_t)b * T_LEN * 256 + d;
  const float* bp = bm    + (size_t)b * T_LEN * 16 + n;

  for (int t = 0; t < T_LEN; t += 4) {
    float dv0 = dp[(t + 0) * 256];
    float dv1 = dp[(t + 1) * 256];
    float dv2 = dp[(t + 2) * 256];
    float dv3 = dp[(t + 3) * 256];
    float xv0 = xp[(t + 0) * 256];
    float xv1 = xp[(t + 1) * 256];
    float xv2 = xp[(t + 2) * 256];
    float xv3 = xp[(t + 3) * 256];
    float bv0 = bp[(t + 0) * 16];
    float bv1 = bp[(t + 1) * 16];
    float bv2 = bp[(t + 2) * 16];
    float bv3 = bp[(t + 3) * 16];
    s = exp2f(dv0 * A2) * s + xv0 * bv0;
    s = exp2f(dv1 * A2) * s + xv1 * bv1;
    s = exp2f(dv2 * A2) * s + xv2 * bv2;
    s = exp2f(dv3 * A2) * s + xv3 * bv3;
  }
  state_out[((size_t)b * 256 + d) * 16 + n] = s;
}

// K5: per-batch head.
__global__ __launch_bounds__(256) void k5_head(
    const float* __restrict__ x, const float* __restrict__ ip_w,
    const float* __restrict__ ip_b, const float* __restrict__ in_proj_w,
    const float* __restrict__ x_proj_w, const float* __restrict__ u,
    const float* __restrict__ state, const float* __restrict__ D_skip,
    const float* __restrict__ out_proj_w, const float* __restrict__ fc1_w,
    const float* __restrict__ fc1_b, const float* __restrict__ fc2_w,
    const float* __restrict__ fc2_b, float* __restrict__ out)
{
  const int b = blockIdx.x, tid = threadIdx.x;
  __shared__ float hl[128], ul[256], zs[256], cm[16], yv[256], ov[128], hid[64];
  if (tid < 128) {
    float acc = ip_b[tid];
    const float* xr = x + ((size_t)b * T_LEN + (T_LEN - 1)) * C_IN_;
#pragma unroll
    for (int c = 0; c < C_IN_; ++c) acc += xr[c] * ip_w[tid * C_IN_ + c];
    hl[tid] = acc;
  }
  ul[tid] = u[((size_t)b * T_LEN + (T_LEN - 1)) * 256 + tid];
  __syncthreads();
  {
    float acc = 0.f;
    const float* w = in_proj_w + (size_t)(256 + tid) * 128;
    for (int k = 0; k < 128; ++k) acc += hl[k] * w[k];
    zs[tid] = acc * sigmoid_f(acc);
  }
  if (tid < 16) {
    float acc = 0.f;
    const float* w = x_proj_w + (size_t)(24 + tid) * 256;
    for (int k = 0; k < 256; ++k) acc += ul[k] * w[k];
    cm[tid] = acc;
  }
  __syncthreads();
  {
    const float* st = state + ((size_t)b * 256 + tid) * 16;
    float acc = 0.f;
#pragma unroll
    for (int n = 0; n < 16; ++n) acc += st[n] * cm[n];
    yv[tid] = (acc + ul[tid] * D_skip[tid]) * zs[tid];
  }
  __syncthreads();
  if (tid < 128) {
    float acc = 0.f;
    const float* w = out_proj_w + (size_t)tid * 256;
    for (int k = 0; k < 256; ++k) acc += yv[k] * w[k];
    ov[tid] = acc;
  }
  __syncthreads();
  if (tid < 64) {
    float acc = fc1_b[tid];
    const float* w = fc1_w + (size_t)tid * 128;
    for (int k = 0; k < 128; ++k) acc += ov[k] * w[k];
    hid[tid] = fmaxf(acc, 0.f);
  }
  __syncthreads();
  if (tid < N_CLS) {
    float acc = fc2_b[tid];
    const float* w = fc2_w + (size_t)tid * 64;
    for (int k = 0; k < 64; ++k) acc += hid[k] * w[k];
    out[b * N_CLS + tid] = acc;
  }
}

extern "C" void kernel_launch(void* const* d_in, const int* in_sizes, int n_in,
                              void* d_out, int out_size, void* d_ws, size_t ws_size,
                              hipStream_t stream) {
  (void)in_sizes; (void)n_in; (void)out_size; (void)ws_size;
  const float* x         = (const float*)d_in[0];
  const float* ip_w      = (const float*)d_in[1];
  const float* ip_b      = (const float*)d_in[2];
  const float* in_proj_w = (const float*)d_in[3];
  const float* conv_w    = (const float*)d_in[4];
  const float* conv_b    = (const float*)d_in[5];
  const float* x_proj_w  = (const float*)d_in[6];
  const float* dt_proj_w = (const float*)d_in[7];
  const float* dt_proj_b = (const float*)d_in[8];
  const float* A_log     = (const float*)d_in[9];
  const float* D_skip    = (const float*)d_in[10];
  const float* out_proj_w= (const float*)d_in[11];
  const float* fc1_w     = (const float*)d_in[12];
  const float* fc1_b     = (const float*)d_in[13];
  const float* fc2_w     = (const float*)d_in[14];
  const float* fc2_b     = (const float*)d_in[15];
  float* out = (float*)d_out;

  float* u     = (float*)d_ws;                       // 64000*256 f32
  float* delta = u + (size_t)64000 * 256;            // 64000*256 f32
  float* du    = delta + (size_t)64000 * 256;        // 64000*256 f32
  float* bm    = du + (size_t)64000 * 256;           // 64000*16 f32
  float* state = bm + (size_t)64000 * 16;            // 64*256*16 f32

  k1_u<<<dim3(16, 64), 256, 0, stream>>>(x, ip_w, ip_b, in_proj_w, conv_w, conv_b, u);
  k3_delta<<<1000, 256, 0, stream>>>(u, x_proj_w, dt_proj_w, dt_proj_b, delta, du, bm);
  k4_scan<<<dim3(16, 64), 256, 0, stream>>>(delta, du, bm, A_log, state);
  k5_head<<<64, 256, 0, stream>>>(x, ip_w, ip_b, in_proj_w, x_proj_w, u, state,
                                  D_skip, out_proj_w, fc1_w, fc1_b, fc2_w, fc2_b, out);
}